// Round 2
// baseline (306.960 us; speedup 1.0000x reference)
//
#include <hip/hip_runtime.h>
#include <cstdint>
#include <cstddef>

// Problem constants
constexpr int Bc = 4;
constexpr int Tc = 4096;
constexpr int Cc = 1024;
constexpr int Hc = 16;
constexpr int Dc = 64;
constexpr int Mc = Bc * Tc;        // 16384 rows
constexpr int N1c = 3 * Cc;        // 3072
constexpr int Kc = Cc;             // 1024
constexpr int KBc = Kc / 32;       // 32 k-tiles

typedef __bf16 bf16x8 __attribute__((ext_vector_type(8)));
typedef float  f32x4  __attribute__((ext_vector_type(4)));
typedef __attribute__((address_space(1))) uint32_t gu32;
typedef __attribute__((address_space(3))) uint32_t lu32;

__device__ __forceinline__ float bf2f(unsigned short u) {
    return __uint_as_float(((unsigned)u) << 16);
}
__device__ __forceinline__ unsigned short f2bf(float f) {
    unsigned u = __float_as_uint(f);
    u += 0x7FFF + ((u >> 16) & 1);   // round-to-nearest-even (finite values)
    return (unsigned short)(u >> 16);
}

__device__ __forceinline__ void load_lds16(const void* g, void* l) {
    // wave-uniform LDS base + lane*16; per-lane global address
    __builtin_amdgcn_global_load_lds((gu32*)(uintptr_t)g, (lu32*)(uintptr_t)l, 16, 0, 0);
}

// ============ packed-fragment layout ============
// A 16(rows)x32(k) tile = 512 bf16 = 64 lanes x 8 elems, contiguous in lane order.
// lane = fq*16 + fr  (fr = row&15, fq = (k&31)>>3), elem j = k&7.
// tile index: (row>>4)*KB + (k>>5). Wave fragment load = tile_base + lane*16B
// -> one coalesced b128 (global) or one conflict-free ds_read_b128 (LDS).

// ---------------- x fp32 [M][K] -> packed bf16 fragments ----------------
__global__ void convert_x_packed(const float* __restrict__ x,
                                 unsigned short* __restrict__ Ap) {
    const int w = threadIdx.x >> 6, lane = threadIdx.x & 63;
    const int t = blockIdx.x * 4 + w;          // tile id = mb*KB + kb
    const int mb = t >> 5, kb = t & 31;
    const int r = lane >> 2, c = lane & 3;
    const float* src = x + (size_t)(mb * 16 + r) * Kc + kb * 32 + c * 8;
    float4 f0 = *(const float4*)src;
    float4 f1 = *(const float4*)(src + 4);
    unsigned short u[8];
    u[0] = f2bf(f0.x); u[1] = f2bf(f0.y); u[2] = f2bf(f0.z); u[3] = f2bf(f0.w);
    u[4] = f2bf(f1.x); u[5] = f2bf(f1.y); u[6] = f2bf(f1.z); u[7] = f2bf(f1.w);
    *(uint4*)(Ap + (size_t)t * 512 + (c * 16 + r) * 8) = *(uint4*)u;
}

// ---------------- W fp32 [K][N] -> packed bf16 fragments (transposed) ----------------
__global__ void transpose_convert_packed(const float* __restrict__ W,
                                         unsigned short* __restrict__ Bp,
                                         int K, int N) {
    __shared__ float tile[32][33];
    const int tx = threadIdx.x, ty = threadIdx.y;
    const int n0 = blockIdx.x * 32, k0 = blockIdx.y * 32;
    for (int i = ty; i < 32; i += 8)
        tile[i][tx] = W[(size_t)(k0 + i) * N + n0 + tx];
    __syncthreads();
    const int t = ty * 32 + tx;
    const int h = t >> 7, rr = t & 127, lane = rr >> 1, half = rr & 1;
    const int fq = lane >> 4, fn = lane & 15;
    unsigned short u[4];
    #pragma unroll
    for (int j = 0; j < 4; ++j)
        u[j] = f2bf(tile[fq * 8 + half * 4 + j][h * 16 + fn]);
    size_t tileIdx = (size_t)((n0 >> 4) + h) * (K >> 5) + (k0 >> 5);
    *(uint2*)(Bp + tileIdx * 512 + lane * 8 + half * 4) = *(uint2*)u;
}

// ---------------- 256x256 8-wave phase-interleaved bf16 MFMA GEMM ----------------
// m201-style phase discipline on the packed-fragment layout (which already
// gives T2's zero bank conflicts). BK=32, double-buffered 64 KB LDS,
// 512 threads = 8 waves in 2(M)x4(N), 128x64 per wave.
//
// Per K-step k (buffer c = k&1):
//  [top]  12 ds_read_b128 (4 B frags + 8 A frags of buf c)  -- issued EARLY
//         issue LATE pair of L(k+1) -> idle buf c^1
//         s_barrier  <- barrier wait ABSORBS the ds_read latency
//         lgkmcnt(0) + sched_barrier; setprio: 16 MFMA (A-half0); s_barrier
//         issue EARLY pair of L(k+2) -> buf c (all reads of buf c are
//         provably retired: every wave passed lgkmcnt(0) before barrier 2)
//         setprio: 16 MFMA (A-half1)
//         s_waitcnt vmcnt(2)  (never 0 mid-loop: 2 newest = early(k+2))
//         s_barrier  <- publishes buf[(k+1)&1]
template <bool OUT_BF16>
__global__ __launch_bounds__(512, 2) void gemm8p_kernel(
    const unsigned short* __restrict__ Ap,
    const unsigned short* __restrict__ Bp,
    const float* __restrict__ bias,
    void* __restrict__ Cout,
    int M, int N, int K, int NBLK) {
    __shared__ unsigned short sA[2][16][512];   // [buf][local mtile][frag]
    __shared__ unsigned short sB[2][16][512];   // [buf][local ntile][frag]
    const int KB = K >> 5;

    // XCD-aware swizzle (grid % 8 == 0 for both GEMMs)
    const int id  = blockIdx.x;
    const int xcd = id & 7;
    const int per = id >> 3;
    const int by  = xcd * ((M >> 8) >> 3) + per / NBLK;
    const int bx  = per % NBLK;

    const int w    = threadIdx.x >> 6;
    const int lane = threadIdx.x & 63;
    const int am   = (w >> 2) * 8;       // A local mtile base (0 or 8)
    const int bn   = (w & 3) * 4;        // B local ntile base
    const int la0  = 2 * w, la1 = 2 * w + 1;    // tiles this wave stages
    const bool earlyA = ((w & 2) == 0);

    // per-lane global fragment pointers (tile base + lane*16B)
    const unsigned short* gA0 = Ap + ((size_t)(by * 16 + la0) * KB) * 512 + lane * 8;
    const unsigned short* gA1 = Ap + ((size_t)(by * 16 + la1) * KB) * 512 + lane * 8;
    const unsigned short* gB0 = Bp + ((size_t)(bx * 16 + la0) * KB) * 512 + lane * 8;
    const unsigned short* gB1 = Bp + ((size_t)(bx * 16 + la1) * KB) * 512 + lane * 8;

    const unsigned short* gE0 = earlyA ? gA0 : gB0;
    const unsigned short* gE1 = earlyA ? gA1 : gB1;
    const unsigned short* gL0 = earlyA ? gB0 : gA0;
    const unsigned short* gL1 = earlyA ? gB1 : gA1;
    unsigned short* const dE0_0 = earlyA ? &sA[0][la0][0] : &sB[0][la0][0];
    unsigned short* const dE1_0 = earlyA ? &sA[0][la1][0] : &sB[0][la1][0];
    unsigned short* const dE0_1 = earlyA ? &sA[1][la0][0] : &sB[1][la0][0];
    unsigned short* const dE1_1 = earlyA ? &sA[1][la1][0] : &sB[1][la1][0];
    unsigned short* const dL0_0 = earlyA ? &sB[0][la0][0] : &sA[0][la0][0];
    unsigned short* const dL1_0 = earlyA ? &sB[0][la1][0] : &sA[0][la1][0];
    unsigned short* const dL0_1 = earlyA ? &sB[1][la0][0] : &sA[1][la0][0];
    unsigned short* const dL1_1 = earlyA ? &sB[1][la1][0] : &sA[1][la1][0];

    // prologue: L_0 complete (4 loads, buf0) + early pair of L_1 (buf1)
    load_lds16(gA0, &sA[0][la0][0]);
    load_lds16(gA1, &sA[0][la1][0]);
    load_lds16(gB0, &sB[0][la0][0]);
    load_lds16(gB1, &sB[0][la1][0]);
    load_lds16(gE0 + 512, dE0_1);
    load_lds16(gE1 + 512, dE1_1);

    const f32x4 zero4 = {0.f, 0.f, 0.f, 0.f};
    f32x4 acc[8][4];
    #pragma unroll
    for (int i = 0; i < 8; ++i)
        #pragma unroll
        for (int j = 0; j < 4; ++j) acc[i][j] = zero4;

    asm volatile("s_waitcnt vmcnt(2)" ::: "memory");   // L_0 landed
    __builtin_amdgcn_s_barrier();

    #pragma unroll 2
    for (int k = 0; k < KB; ++k) {
        const int c = k & 1;
        const unsigned short* sAc = &sA[c][0][0];
        const unsigned short* sBc = &sB[c][0][0];
        bf16x8 af[8], bfr[4];

        // ---- all reads for this K-step, issued before the barrier ----
        #pragma unroll
        for (int ni = 0; ni < 4; ++ni)
            bfr[ni] = *(const bf16x8*)(sBc + (bn + ni) * 512 + lane * 8);
        #pragma unroll
        for (int mi = 0; mi < 8; ++mi)
            af[mi] = *(const bf16x8*)(sAc + (am + mi) * 512 + lane * 8);
        if (k + 1 < KB) {   // late pair of L(k+1) -> idle buffer c^1
            const size_t o = (size_t)(k + 1) * 512;
            load_lds16(gL0 + o, c ? dL0_0 : dL0_1);
            load_lds16(gL1 + o, c ? dL1_0 : dL1_1);
        }
        __builtin_amdgcn_sched_barrier(0);
        __builtin_amdgcn_s_barrier();                    // absorbs read latency
        asm volatile("s_waitcnt lgkmcnt(0)" ::: "memory");
        __builtin_amdgcn_sched_barrier(0);

        __builtin_amdgcn_s_setprio(1);
        #pragma unroll
        for (int mi = 0; mi < 4; ++mi)
            #pragma unroll
            for (int ni = 0; ni < 4; ++ni)
                acc[mi][ni] = __builtin_amdgcn_mfma_f32_16x16x32_bf16(
                    af[mi], bfr[ni], acc[mi][ni], 0, 0, 0);
        __builtin_amdgcn_s_setprio(0);
        __builtin_amdgcn_sched_barrier(0);
        __builtin_amdgcn_s_barrier();                    // all reads of buf c retired

        if (k + 2 < KB) {   // early pair of L(k+2) -> buf c (now safe anywhere)
            const size_t o = (size_t)(k + 2) * 512;
            load_lds16(gE0 + o, c ? dE0_1 : dE0_0);
            load_lds16(gE1 + o, c ? dE1_1 : dE1_0);
        }
        __builtin_amdgcn_s_setprio(1);
        #pragma unroll
        for (int mi = 0; mi < 4; ++mi)
            #pragma unroll
            for (int ni = 0; ni < 4; ++ni)
                acc[4 + mi][ni] = __builtin_amdgcn_mfma_f32_16x16x32_bf16(
                    af[4 + mi], bfr[ni], acc[4 + mi][ni], 0, 0, 0);
        __builtin_amdgcn_s_setprio(0);
        if (k + 2 < KB)
            asm volatile("s_waitcnt vmcnt(2)" ::: "memory");  // L(k+1) landed
        else
            asm volatile("s_waitcnt vmcnt(0)" ::: "memory");  // tail drain
        __builtin_amdgcn_s_barrier();                    // publishes buf[(k+1)&1]
    }

    // epilogue: D row = (lane>>4)*4 + reg, col = lane&15
    const int fr = lane & 15;
    const int fq = lane >> 4;
    const int m0 = by * 256 + (w >> 2) * 128;
    const int n0 = bx * 256 + (w & 3) * 64;
    #pragma unroll
    for (int mi = 0; mi < 8; ++mi) {
        #pragma unroll
        for (int ni = 0; ni < 4; ++ni) {
            int row = m0 + mi * 16 + fq * 4;
            int col = n0 + ni * 16 + fr;
            float bb = bias[col];
            #pragma unroll
            for (int r = 0; r < 4; ++r) {
                float v = acc[mi][ni][r] + bb;
                if (OUT_BF16)
                    ((unsigned short*)Cout)[(size_t)(row + r) * N + col] = f2bf(v);
                else
                    ((float*)Cout)[(size_t)(row + r) * N + col] = v;
            }
        }
    }
}

// ---------------- per-token head-axis attention, MFMA, packed-fragment out ----------------
// One wave per token; output staged in LDS (sO) then written with 2 coalesced
// dwordx4 stores per lane (was: 16 scattered 2B global stores per lane).
__global__ __launch_bounds__(256) void attn_mfma_kernel(
    const unsigned short* __restrict__ qkv,
    unsigned short* __restrict__ attP) {
    // per-token: sV [16][72] 2304B | sP [16][20] f32 1280B | sO 1152 shorts 2304B
    __shared__ char smem[4 * 5888];
    const int w    = threadIdx.x >> 6;
    const int lane = threadIdx.x & 63;
    const int m    = lane & 15;
    const int q    = lane >> 4;
    const int row  = blockIdx.x * 4 + w;
    unsigned short* sV = (unsigned short*)(smem + w * 5888);
    float*          sP = (float*)(smem + w * 5888 + 2304);
    unsigned short* sO = (unsigned short*)(smem + w * 5888 + 3584);

    const unsigned short* src = qkv + (size_t)row * 3072;

    bf16x8 aq0 = *(const bf16x8*)(src + m * 64 + q * 8);
    bf16x8 aq1 = *(const bf16x8*)(src + m * 64 + 32 + q * 8);
    bf16x8 bk0 = *(const bf16x8*)(src + 1024 + m * 64 + q * 8);
    bf16x8 bk1 = *(const bf16x8*)(src + 1024 + m * 64 + 32 + q * 8);

    #pragma unroll
    for (int t = 0; t < 2; ++t) {
        int G = t * 64 + lane;
        int r = G >> 3, p = G & 7;
        *(uint4*)(sV + r * 72 + p * 8) = *(const uint4*)(src + 2048 + G * 8);
    }

    f32x4 s = {0.f, 0.f, 0.f, 0.f};
    s = __builtin_amdgcn_mfma_f32_16x16x32_bf16(aq0, bk0, s, 0, 0, 0);
    s = __builtin_amdgcn_mfma_f32_16x16x32_bf16(aq1, bk1, s, 0, 0, 0);

    #pragma unroll
    for (int r = 0; r < 4; ++r) {
        float t0 = s[r] * 0.125f;
        float mx = t0;
        mx = fmaxf(mx, __shfl_xor(mx, 1));
        mx = fmaxf(mx, __shfl_xor(mx, 2));
        mx = fmaxf(mx, __shfl_xor(mx, 4));
        mx = fmaxf(mx, __shfl_xor(mx, 8));
        float e = __expf(t0 - mx);
        float su = e;
        su += __shfl_xor(su, 1);
        su += __shfl_xor(su, 2);
        su += __shfl_xor(su, 4);
        su += __shfl_xor(su, 8);
        sP[(q * 4 + r) * 20 + m] = e / su;
    }
    __syncthreads();

    const float* pr = sP + m * 20 + (q & 1) * 8;
    float4 pf0 = *(const float4*)(pr);
    float4 pf1 = *(const float4*)(pr + 4);
    const bool act = (q < 2);
    union { unsigned short u[8]; bf16x8 b; } pa;
    pa.u[0] = act ? f2bf(pf0.x) : 0;
    pa.u[1] = act ? f2bf(pf0.y) : 0;
    pa.u[2] = act ? f2bf(pf0.z) : 0;
    pa.u[3] = act ? f2bf(pf0.w) : 0;
    pa.u[4] = act ? f2bf(pf1.x) : 0;
    pa.u[5] = act ? f2bf(pf1.y) : 0;
    pa.u[6] = act ? f2bf(pf1.z) : 0;
    pa.u[7] = act ? f2bf(pf1.w) : 0;

    const unsigned short* vb = sV + (q & 1) * 8 * 72;
    #pragma unroll
    for (int c4 = 0; c4 < 4; ++c4) {
        union { unsigned short u[8]; bf16x8 b; } vf;
        #pragma unroll
        for (int j = 0; j < 8; ++j) vf.u[j] = vb[j * 72 + c4 * 16 + m];
        f32x4 o = {0.f, 0.f, 0.f, 0.f};
        o = __builtin_amdgcn_mfma_f32_16x16x32_bf16(pa.b, vf.b, o, 0, 0, 0);
        #pragma unroll
        for (int r = 0; r < 4; ++r) {
            int col = (q * 4 + r) * 64 + c4 * 16 + m;   // k index in [0,1024)
            sO[col + ((col >> 6) << 3)] = f2bf(o[r]);   // pad 8 shorts per 64
        }
    }
    __syncthreads();   // ensure sO writes retired before cross-lane reads

    // packed-fragment write-out: 2 x dwordx4 per lane, 16B-aligned
    const size_t tileBase = (size_t)(row >> 4) * 32 * 512;   // token's m-block (KB=32)
    const int fr_tok = row & 15;
    #pragma unroll
    for (int t = 0; t < 2; ++t) {
        int j = t * 64 + lane;                               // col group j*8..j*8+7
        uint4 val = *(const uint4*)(sO + j * 8 + ((j >> 3) << 3));
        *(uint4*)(attP + tileBase + (size_t)(j >> 2) * 512
                  + ((j & 3) * 16 + fr_tok) * 8) = val;
    }
}

extern "C" void kernel_launch(void* const* d_in, const int* in_sizes, int n_in,
                              void* d_out, int out_size, void* d_ws, size_t ws_size,
                              hipStream_t stream) {
    const float* x    = (const float*)d_in[0];
    const float* Wqkv = (const float*)d_in[1];
    const float* bqkv = (const float*)d_in[2];
    const float* Wout = (const float*)d_in[3];
    const float* bout = (const float*)d_in[4];
    float* out = (float*)d_out;

    // workspace: xp 32M | Wqkv_p 6M | Wout_p 2M | qkv 96M = ~136 MB
    char* ws = (char*)d_ws;
    unsigned short* xp   = (unsigned short*)ws;                 ws += (size_t)Mc * Kc * 2;
    unsigned short* Wqkp = (unsigned short*)ws;                 ws += (size_t)N1c * Kc * 2;
    unsigned short* Wop  = (unsigned short*)ws;                 ws += (size_t)Cc * Kc * 2;
    unsigned short* qkv  = (unsigned short*)ws;
    unsigned short* attP = xp;   // alias: xp dead after GEMM1

    // 1) x -> packed bf16 fragments
    convert_x_packed<<<(Mc / 16) * KBc / 4, 256, 0, stream>>>(x, xp);
    // 2) weights -> packed bf16 fragments (transposed)
    transpose_convert_packed<<<dim3(N1c / 32, Kc / 32), dim3(32, 8), 0, stream>>>(Wqkv, Wqkp, Kc, N1c);
    transpose_convert_packed<<<dim3(Cc / 32, Kc / 32), dim3(32, 8), 0, stream>>>(Wout, Wop, Kc, Cc);
    // 3) qkv = x @ W_qkv + b_qkv   (bf16 row-major out), 64x12 blocks
    gemm8p_kernel<true><<<(Mc / 256) * (N1c / 256), 512, 0, stream>>>(
        xp, Wqkp, bqkv, qkv, Mc, N1c, Kc, N1c / 256);
    // 4) head-axis attention per token (MFMA), writes packed-fragment A
    attn_mfma_kernel<<<Mc / 4, 256, 0, stream>>>(qkv, attP);
    // 5) out = att @ W_out + b_out (fp32 row-major out), 64x4 blocks
    gemm8p_kernel<false><<<(Mc / 256) * (Cc / 256), 512, 0, stream>>>(
        attP, Wop, bout, out, Mc, Cc, Kc, Cc / 256);
}

// Round 3
// 303.321 us; speedup vs baseline: 1.0120x; 1.0120x over previous
//
#include <hip/hip_runtime.h>
#include <cstdint>
#include <cstddef>

// Problem constants
constexpr int Bc = 4;
constexpr int Tc = 4096;
constexpr int Cc = 1024;
constexpr int Hc = 16;
constexpr int Dc = 64;
constexpr int Mc = Bc * Tc;        // 16384 rows
constexpr int N1c = 3 * Cc;        // 3072
constexpr int Kc = Cc;             // 1024
constexpr int KBc = Kc / 32;       // 32 k-tiles

typedef __bf16 bf16x8 __attribute__((ext_vector_type(8)));
typedef float  f32x4  __attribute__((ext_vector_type(4)));
typedef __attribute__((address_space(1))) uint32_t gu32;
typedef __attribute__((address_space(3))) uint32_t lu32;

__device__ __forceinline__ float bf2f(unsigned short u) {
    return __uint_as_float(((unsigned)u) << 16);
}
__device__ __forceinline__ unsigned short f2bf(float f) {
    unsigned u = __float_as_uint(f);
    u += 0x7FFF + ((u >> 16) & 1);   // round-to-nearest-even (finite values)
    return (unsigned short)(u >> 16);
}

__device__ __forceinline__ void load_lds16(const void* g, void* l) {
    // wave-uniform LDS base + lane*16; per-lane global address
    __builtin_amdgcn_global_load_lds((gu32*)(uintptr_t)g, (lu32*)(uintptr_t)l, 16, 0, 0);
}

// ============ packed-fragment layout ============
// A 16(rows)x32(k) tile = 512 bf16 = 64 lanes x 8 elems, contiguous in lane order.
// lane = fq*16 + fr  (fr = row&15, fq = (k&31)>>3), elem j = k&7.
// tile index: (row>>4)*KB + (k>>5). Wave fragment load = tile_base + lane*16B
// -> one coalesced b128 (global) or one conflict-free ds_read_b128 (LDS).

// ---------------- x fp32 [M][K] -> packed bf16 fragments ----------------
__global__ void convert_x_packed(const float* __restrict__ x,
                                 unsigned short* __restrict__ Ap) {
    const int w = threadIdx.x >> 6, lane = threadIdx.x & 63;
    const int t = blockIdx.x * 4 + w;          // tile id = mb*KB + kb
    const int mb = t >> 5, kb = t & 31;
    const int r = lane >> 2, c = lane & 3;
    const float* src = x + (size_t)(mb * 16 + r) * Kc + kb * 32 + c * 8;
    float4 f0 = *(const float4*)src;
    float4 f1 = *(const float4*)(src + 4);
    unsigned short u[8];
    u[0] = f2bf(f0.x); u[1] = f2bf(f0.y); u[2] = f2bf(f0.z); u[3] = f2bf(f0.w);
    u[4] = f2bf(f1.x); u[5] = f2bf(f1.y); u[6] = f2bf(f1.z); u[7] = f2bf(f1.w);
    *(uint4*)(Ap + (size_t)t * 512 + (c * 16 + r) * 8) = *(uint4*)u;
}

// ---------------- W fp32 [K][N] -> packed bf16 fragments (transposed) ----------------
__global__ void transpose_convert_packed(const float* __restrict__ W,
                                         unsigned short* __restrict__ Bp,
                                         int K, int N) {
    __shared__ float tile[32][33];
    const int tx = threadIdx.x, ty = threadIdx.y;
    const int n0 = blockIdx.x * 32, k0 = blockIdx.y * 32;
    for (int i = ty; i < 32; i += 8)
        tile[i][tx] = W[(size_t)(k0 + i) * N + n0 + tx];
    __syncthreads();
    const int t = ty * 32 + tx;
    const int h = t >> 7, rr = t & 127, lane = rr >> 1, half = rr & 1;
    const int fq = lane >> 4, fn = lane & 15;
    unsigned short u[4];
    #pragma unroll
    for (int j = 0; j < 4; ++j)
        u[j] = f2bf(tile[fq * 8 + half * 4 + j][h * 16 + fn]);
    size_t tileIdx = (size_t)((n0 >> 4) + h) * (K >> 5) + (k0 >> 5);
    *(uint2*)(Bp + tileIdx * 512 + lane * 8 + half * 4) = *(uint2*)u;
}

// ---------------- 256x256 triple-buffered bf16 MFMA GEMM (distance-2 prefetch) ----
// 512 threads = 8 waves (2M x 4N), 128x64 per wave, BK=32.
// LDS: 3 buffers x (16 A-tiles + 16 B-tiles) x 1KB = 96 KB (dynamic).
// Per K-step k (cur = k%3, stg = (k+2)%3):
//   issue 4 global_load_lds for step k+2 -> buf stg   (slack ~2 steps >> HBM lat)
//   12 ds_read_b128 from buf cur
//   s_barrier; lgkmcnt(0)+sched_barrier; setprio(1); 32 MFMA; setprio(0)
//   s_waitcnt vmcnt(4)   (counted: drains k+1's 4 loads, keeps k+2's in flight)
//   s_barrier            (publishes buf (k+1)%3)
// Race-freedom: buf stg == buf (k-1)%3 whose reads all retired before any wave
// passed step k-1's closing barrier; every wave's vmcnt(4) precedes the
// publishing barrier, so cross-wave staged tiles are landed before use.
template <bool OUT_BF16>
__global__ __launch_bounds__(512, 2) void gemm3b_kernel(
    const unsigned short* __restrict__ Ap,
    const unsigned short* __restrict__ Bp,
    const float* __restrict__ bias,
    void* __restrict__ Cout,
    int M, int N, int K, int NBLK) {
    extern __shared__ unsigned short smem3[];   // 49152 shorts = 96 KB
    unsigned short* const sA = smem3;           // [3][16][512]
    unsigned short* const sB = smem3 + 3 * 16 * 512;
    const int KB = K >> 5;

    // XCD-aware swizzle (grid % 8 == 0 for both GEMMs)
    const int id  = blockIdx.x;
    const int xcd = id & 7;
    const int per = id >> 3;
    const int by  = xcd * ((M >> 8) >> 3) + per / NBLK;
    const int bx  = per % NBLK;

    const int w    = threadIdx.x >> 6;
    const int lane = threadIdx.x & 63;
    const int am   = (w >> 2) * 8;       // A local mtile base (0 or 8)
    const int bn   = (w & 3) * 4;        // B local ntile base
    const int la0  = 2 * w, la1 = 2 * w + 1;    // tiles this wave stages

    // per-lane global fragment pointers (tile base + lane*16B)
    const unsigned short* gA0 = Ap + ((size_t)(by * 16 + la0) * KB) * 512 + lane * 8;
    const unsigned short* gA1 = Ap + ((size_t)(by * 16 + la1) * KB) * 512 + lane * 8;
    const unsigned short* gB0 = Bp + ((size_t)(bx * 16 + la0) * KB) * 512 + lane * 8;
    const unsigned short* gB1 = Bp + ((size_t)(bx * 16 + la1) * KB) * 512 + lane * 8;

    // LDS stage destinations per buffer (wave-uniform base; DMA adds lane*16B)
    unsigned short* const dA0[3] = { sA + la0 * 512,             sA + 8192 + la0 * 512,
                                     sA + 16384 + la0 * 512 };
    unsigned short* const dA1[3] = { sA + la1 * 512,             sA + 8192 + la1 * 512,
                                     sA + 16384 + la1 * 512 };
    unsigned short* const dB0[3] = { sB + la0 * 512,             sB + 8192 + la0 * 512,
                                     sB + 16384 + la0 * 512 };
    unsigned short* const dB1[3] = { sB + la1 * 512,             sB + 8192 + la1 * 512,
                                     sB + 16384 + la1 * 512 };

    // prologue: stage step 0 -> buf0, step 1 -> buf1
    load_lds16(gA0, dA0[0]); load_lds16(gA1, dA1[0]);
    load_lds16(gB0, dB0[0]); load_lds16(gB1, dB1[0]);
    load_lds16(gA0 + 512, dA0[1]); load_lds16(gA1 + 512, dA1[1]);
    load_lds16(gB0 + 512, dB0[1]); load_lds16(gB1 + 512, dB1[1]);

    const f32x4 zero4 = {0.f, 0.f, 0.f, 0.f};
    f32x4 acc[8][4];
    #pragma unroll
    for (int i = 0; i < 8; ++i)
        #pragma unroll
        for (int j = 0; j < 4; ++j) acc[i][j] = zero4;

    asm volatile("s_waitcnt vmcnt(4)" ::: "memory");   // step-0 tiles landed
    __builtin_amdgcn_s_barrier();

    int cur = 0, stg = 2;
    #pragma unroll 1
    for (int k = 0; k < KB; ++k) {
        // stage step k+2 -> buf stg (issued first: earliest memory)
        if (k + 2 < KB) {
            const size_t o = (size_t)(k + 2) * 512;
            load_lds16(gA0 + o, dA0[stg]); load_lds16(gA1 + o, dA1[stg]);
            load_lds16(gB0 + o, dB0[stg]); load_lds16(gB1 + o, dB1[stg]);
        }

        const unsigned short* sAc = sA + cur * 8192;
        const unsigned short* sBc = sB + cur * 8192;
        bf16x8 af[8], bfr[4];
        #pragma unroll
        for (int ni = 0; ni < 4; ++ni)
            bfr[ni] = *(const bf16x8*)(sBc + (bn + ni) * 512 + lane * 8);
        #pragma unroll
        for (int mi = 0; mi < 8; ++mi)
            af[mi] = *(const bf16x8*)(sAc + (am + mi) * 512 + lane * 8);

        __builtin_amdgcn_sched_barrier(0);
        __builtin_amdgcn_s_barrier();
        asm volatile("s_waitcnt lgkmcnt(0)" ::: "memory");
        __builtin_amdgcn_sched_barrier(0);

        __builtin_amdgcn_s_setprio(1);
        #pragma unroll
        for (int mi = 0; mi < 8; ++mi)
            #pragma unroll
            for (int ni = 0; ni < 4; ++ni)
                acc[mi][ni] = __builtin_amdgcn_mfma_f32_16x16x32_bf16(
                    af[mi], bfr[ni], acc[mi][ni], 0, 0, 0);
        __builtin_amdgcn_s_setprio(0);

        if (k + 2 < KB)
            asm volatile("s_waitcnt vmcnt(4)" ::: "memory");  // k+1's tiles landed
        else
            asm volatile("s_waitcnt vmcnt(0)" ::: "memory");  // tail drain
        __builtin_amdgcn_s_barrier();                          // publish buf (k+1)%3

        cur = (cur == 2) ? 0 : cur + 1;
        stg = (stg == 2) ? 0 : stg + 1;
    }

    // epilogue: D row = (lane>>4)*4 + reg, col = lane&15
    const int fr = lane & 15;
    const int fq = lane >> 4;
    const int m0 = by * 256 + (w >> 2) * 128;
    const int n0 = bx * 256 + (w & 3) * 64;
    #pragma unroll
    for (int mi = 0; mi < 8; ++mi) {
        #pragma unroll
        for (int ni = 0; ni < 4; ++ni) {
            int row = m0 + mi * 16 + fq * 4;
            int col = n0 + ni * 16 + fr;
            float bb = bias[col];
            #pragma unroll
            for (int r = 0; r < 4; ++r) {
                float v = acc[mi][ni][r] + bb;
                if (OUT_BF16)
                    ((unsigned short*)Cout)[(size_t)(row + r) * N + col] = f2bf(v);
                else
                    ((float*)Cout)[(size_t)(row + r) * N + col] = v;
            }
        }
    }
}

// ---------------- round-0 fallback GEMM (128x128, 4 waves, static 16KB LDS) ----
template <bool OUT_BF16>
__global__ __launch_bounds__(256, 4) void lds_gemm_kernel(
    const unsigned short* __restrict__ Ap,
    const unsigned short* __restrict__ Bp,
    const float* __restrict__ bias,
    void* __restrict__ Cout,
    int M, int N, int K, int NB) {
    __shared__ unsigned short sA[8 * 512];
    __shared__ unsigned short sB[8 * 512];
    const int KB = K >> 5;
    const int MB = M >> 7;
    const int id   = blockIdx.x;
    const int xcd  = id & 7;
    const int per  = id >> 3;
    const int MSTR = MB >> 3;
    const int byl  = per & 7;
    const int bx   = (per >> 3) % NB;
    const int pass = per / (8 * NB);
    const int by   = xcd * MSTR + pass * 8 + byl;

    const int w    = threadIdx.x >> 6;
    const int lane = threadIdx.x & 63;
    const int m0 = by * 128;
    const int n0 = bx * 128;
    const int wm = (w >> 1) * 64;
    const int wn = (w & 1) * 64;

    const unsigned short* gA0 = Ap + ((size_t)(by * 8 + w    ) * KB) * 512 + lane * 8;
    const unsigned short* gA1 = Ap + ((size_t)(by * 8 + w + 4) * KB) * 512 + lane * 8;
    const unsigned short* gB0 = Bp + ((size_t)(bx * 8 + w    ) * KB) * 512 + lane * 8;
    const unsigned short* gB1 = Bp + ((size_t)(bx * 8 + w + 4) * KB) * 512 + lane * 8;
    unsigned short* lA0 = sA + (w    ) * 512;
    unsigned short* lA1 = sA + (w + 4) * 512;
    unsigned short* lB0 = sB + (w    ) * 512;
    unsigned short* lB1 = sB + (w + 4) * 512;

    const unsigned short* aP = sA + (wm >> 4) * 512 + lane * 8;
    const unsigned short* bP = sB + (wn >> 4) * 512 + lane * 8;

    const f32x4 zero4 = {0.f, 0.f, 0.f, 0.f};
    f32x4 acc[4][4];
    #pragma unroll
    for (int i = 0; i < 4; ++i)
        #pragma unroll
        for (int j = 0; j < 4; ++j) acc[i][j] = zero4;

    #pragma unroll 1
    for (int kb = 0; kb < KB; ++kb) {
        load_lds16(gA0, lA0);
        load_lds16(gA1, lA1);
        load_lds16(gB0, lB0);
        load_lds16(gB1, lB1);
        gA0 += 512; gA1 += 512; gB0 += 512; gB1 += 512;
        __syncthreads();

        bf16x8 af[4], bfr[4];
        #pragma unroll
        for (int mi = 0; mi < 4; ++mi) af[mi]  = *(const bf16x8*)(aP + mi * 512);
        #pragma unroll
        for (int ni = 0; ni < 4; ++ni) bfr[ni] = *(const bf16x8*)(bP + ni * 512);
        #pragma unroll
        for (int mi = 0; mi < 4; ++mi)
            #pragma unroll
            for (int ni = 0; ni < 4; ++ni)
                acc[mi][ni] = __builtin_amdgcn_mfma_f32_16x16x32_bf16(
                    af[mi], bfr[ni], acc[mi][ni], 0, 0, 0);
        __syncthreads();
    }

    const int fr = lane & 15;
    const int fq = lane >> 4;
    #pragma unroll
    for (int mi = 0; mi < 4; ++mi) {
        #pragma unroll
        for (int ni = 0; ni < 4; ++ni) {
            int row = m0 + wm + mi * 16 + fq * 4;
            int col = n0 + wn + ni * 16 + fr;
            float bb = bias[col];
            #pragma unroll
            for (int r = 0; r < 4; ++r) {
                float v = acc[mi][ni][r] + bb;
                if (OUT_BF16)
                    ((unsigned short*)Cout)[(size_t)(row + r) * N + col] = f2bf(v);
                else
                    ((float*)Cout)[(size_t)(row + r) * N + col] = v;
            }
        }
    }
}

// ---------------- per-token head-axis attention, MFMA, packed-fragment out ----------------
// One wave per token; output written directly in packed-fragment layout so it
// feeds the GEMM as A (no repack pass).  (round-0 verified version)
__global__ __launch_bounds__(256) void attn_mfma_kernel(
    const unsigned short* __restrict__ qkv,
    unsigned short* __restrict__ attP) {
    __shared__ char smem[4 * 3584];
    const int w    = threadIdx.x >> 6;
    const int lane = threadIdx.x & 63;
    const int m    = lane & 15;
    const int q    = lane >> 4;
    const int row  = blockIdx.x * 4 + w;
    unsigned short* sV = (unsigned short*)(smem + w * 3584);        // [16][72] bf16
    float*          sP = (float*)(smem + w * 3584 + 2304);          // [16][20] fp32

    const unsigned short* src = qkv + (size_t)row * 3072;

    bf16x8 aq0 = *(const bf16x8*)(src + m * 64 + q * 8);
    bf16x8 aq1 = *(const bf16x8*)(src + m * 64 + 32 + q * 8);
    bf16x8 bk0 = *(const bf16x8*)(src + 1024 + m * 64 + q * 8);
    bf16x8 bk1 = *(const bf16x8*)(src + 1024 + m * 64 + 32 + q * 8);

    #pragma unroll
    for (int t = 0; t < 2; ++t) {
        int G = t * 64 + lane;
        int r = G >> 3, p = G & 7;
        *(uint4*)(sV + r * 72 + p * 8) = *(const uint4*)(src + 2048 + G * 8);
    }

    f32x4 s = {0.f, 0.f, 0.f, 0.f};
    s = __builtin_amdgcn_mfma_f32_16x16x32_bf16(aq0, bk0, s, 0, 0, 0);
    s = __builtin_amdgcn_mfma_f32_16x16x32_bf16(aq1, bk1, s, 0, 0, 0);

    #pragma unroll
    for (int r = 0; r < 4; ++r) {
        float t0 = s[r] * 0.125f;
        float mx = t0;
        mx = fmaxf(mx, __shfl_xor(mx, 1));
        mx = fmaxf(mx, __shfl_xor(mx, 2));
        mx = fmaxf(mx, __shfl_xor(mx, 4));
        mx = fmaxf(mx, __shfl_xor(mx, 8));
        float e = __expf(t0 - mx);
        float su = e;
        su += __shfl_xor(su, 1);
        su += __shfl_xor(su, 2);
        su += __shfl_xor(su, 4);
        su += __shfl_xor(su, 8);
        sP[(q * 4 + r) * 20 + m] = e / su;
    }
    __syncthreads();

    const float* pr = sP + m * 20 + (q & 1) * 8;
    float4 pf0 = *(const float4*)(pr);
    float4 pf1 = *(const float4*)(pr + 4);
    const bool act = (q < 2);
    union { unsigned short u[8]; bf16x8 b; } pa;
    pa.u[0] = act ? f2bf(pf0.x) : 0;
    pa.u[1] = act ? f2bf(pf0.y) : 0;
    pa.u[2] = act ? f2bf(pf0.z) : 0;
    pa.u[3] = act ? f2bf(pf0.w) : 0;
    pa.u[4] = act ? f2bf(pf1.x) : 0;
    pa.u[5] = act ? f2bf(pf1.y) : 0;
    pa.u[6] = act ? f2bf(pf1.z) : 0;
    pa.u[7] = act ? f2bf(pf1.w) : 0;

    const unsigned short* vb = sV + (q & 1) * 8 * 72;
    const size_t tileBase = (size_t)(row >> 4) * 32 * 512;   // token's m-block row (KB=32)
    const int fr_tok = row & 15;
    #pragma unroll
    for (int c4 = 0; c4 < 4; ++c4) {
        union { unsigned short u[8]; bf16x8 b; } vf;
        #pragma unroll
        for (int j = 0; j < 8; ++j) vf.u[j] = vb[j * 72 + c4 * 16 + m];
        f32x4 o = {0.f, 0.f, 0.f, 0.f};
        o = __builtin_amdgcn_mfma_f32_16x16x32_bf16(pa.b, vf.b, o, 0, 0, 0);
        #pragma unroll
        for (int r = 0; r < 4; ++r) {
            int col = (q * 4 + r) * 64 + c4 * 16 + m;        // k index in [0,1024)
            size_t off = tileBase + (size_t)(col >> 5) * 512
                       + (((col >> 3) & 3) * 16 + fr_tok) * 8 + (col & 7);
            attP[off] = f2bf(o[r]);
        }
    }
}

extern "C" void kernel_launch(void* const* d_in, const int* in_sizes, int n_in,
                              void* d_out, int out_size, void* d_ws, size_t ws_size,
                              hipStream_t stream) {
    const float* x    = (const float*)d_in[0];
    const float* Wqkv = (const float*)d_in[1];
    const float* bqkv = (const float*)d_in[2];
    const float* Wout = (const float*)d_in[3];
    const float* bout = (const float*)d_in[4];
    float* out = (float*)d_out;

    // workspace: xp 32M | Wqkv_p 6M | Wout_p 2M | qkv 96M = ~136 MB
    char* ws = (char*)d_ws;
    unsigned short* xp   = (unsigned short*)ws;                 ws += (size_t)Mc * Kc * 2;
    unsigned short* Wqkp = (unsigned short*)ws;                 ws += (size_t)N1c * Kc * 2;
    unsigned short* Wop  = (unsigned short*)ws;                 ws += (size_t)Cc * Kc * 2;
    unsigned short* qkv  = (unsigned short*)ws;
    unsigned short* attP = xp;   // alias: xp dead after GEMM1

    // one-time opt-in to 96 KB dynamic LDS; fall back to round-0 GEMM on failure
    constexpr int DYN_LDS = 3 * 16 * 512 * 2 * 2;   // 98304 B
    static int dyn_ok = -1;
    if (dyn_ok < 0) {
        hipError_t e1 = hipFuncSetAttribute(
            reinterpret_cast<const void*>(gemm3b_kernel<true>),
            hipFuncAttributeMaxDynamicSharedMemorySize, DYN_LDS);
        hipError_t e2 = hipFuncSetAttribute(
            reinterpret_cast<const void*>(gemm3b_kernel<false>),
            hipFuncAttributeMaxDynamicSharedMemorySize, DYN_LDS);
        dyn_ok = (e1 == hipSuccess && e2 == hipSuccess) ? 1 : 0;
    }

    // 1) x -> packed bf16 fragments
    convert_x_packed<<<(Mc / 16) * KBc / 4, 256, 0, stream>>>(x, xp);
    // 2) weights -> packed bf16 fragments (transposed)
    transpose_convert_packed<<<dim3(N1c / 32, Kc / 32), dim3(32, 8), 0, stream>>>(Wqkv, Wqkp, Kc, N1c);
    transpose_convert_packed<<<dim3(Cc / 32, Kc / 32), dim3(32, 8), 0, stream>>>(Wout, Wop, Kc, Cc);

    // 3) qkv = x @ W_qkv + b_qkv   (bf16 row-major out)
    if (dyn_ok)
        gemm3b_kernel<true><<<(Mc / 256) * (N1c / 256), 512, DYN_LDS, stream>>>(
            xp, Wqkp, bqkv, qkv, Mc, N1c, Kc, N1c / 256);
    else
        lds_gemm_kernel<true><<<(N1c / 128) * (Mc / 128), 256, 0, stream>>>(
            xp, Wqkp, bqkv, qkv, Mc, N1c, Kc, N1c / 128);

    // 4) head-axis attention per token (MFMA), writes packed-fragment A
    attn_mfma_kernel<<<Mc / 4, 256, 0, stream>>>(qkv, attP);

    // 5) out = att @ W_out + b_out (fp32 row-major out)
    if (dyn_ok)
        gemm3b_kernel<false><<<(Mc / 256) * (Cc / 256), 512, DYN_LDS, stream>>>(
            attP, Wop, bout, out, Mc, Cc, Kc, Cc / 256);
    else
        lds_gemm_kernel<false><<<(Cc / 128) * (Mc / 128), 256, 0, stream>>>(
            attP, Wop, bout, out, Mc, Cc, Kc, Cc / 128);
}

// Round 5
// 303.005 us; speedup vs baseline: 1.0131x; 1.0010x over previous
//
#include <hip/hip_runtime.h>
#include <cstdint>
#include <cstddef>

// Problem constants
constexpr int Bc = 4;
constexpr int Tc = 4096;
constexpr int Cc = 1024;
constexpr int Hc = 16;
constexpr int Dc = 64;
constexpr int Mc = Bc * Tc;        // 16384 rows
constexpr int N1c = 3 * Cc;        // 3072
constexpr int Kc = Cc;             // 1024
constexpr int KBc = Kc / 32;       // 32 k-tiles

typedef __bf16 bf16x8 __attribute__((ext_vector_type(8)));
typedef float  f32x4  __attribute__((ext_vector_type(4)));
typedef __attribute__((address_space(1))) uint32_t gu32;
typedef __attribute__((address_space(3))) uint32_t lu32;

__device__ __forceinline__ float bf2f(unsigned short u) {
    return __uint_as_float(((unsigned)u) << 16);
}
__device__ __forceinline__ unsigned short f2bf(float f) {
    unsigned u = __float_as_uint(f);
    u += 0x7FFF + ((u >> 16) & 1);   // round-to-nearest-even (finite values)
    return (unsigned short)(u >> 16);
}

__device__ __forceinline__ void load_lds16(const void* g, void* l) {
    // wave-uniform LDS base + lane*16; per-lane global address
    __builtin_amdgcn_global_load_lds((gu32*)(uintptr_t)g, (lu32*)(uintptr_t)l, 16, 0, 0);
}

// ============ packed-fragment layout ============
// A 16(rows)x32(k) tile = 512 bf16 = 64 lanes x 8 elems, contiguous in lane order.
// lane = fq*16 + fr  (fr = row&15, fq = (k&31)>>3), elem j = k&7.
// tile index: (row>>4)*KB + (k>>5). Wave fragment load = tile_base + lane*16B
// -> one coalesced b128 (global) or one conflict-free ds_read_b128 (LDS).

// ---------------- x fp32 [M][K] -> packed bf16 fragments ----------------
__global__ void convert_x_packed(const float* __restrict__ x,
                                 unsigned short* __restrict__ Ap) {
    const int w = threadIdx.x >> 6, lane = threadIdx.x & 63;
    const int t = blockIdx.x * 4 + w;          // tile id = mb*KB + kb
    const int mb = t >> 5, kb = t & 31;
    const int r = lane >> 2, c = lane & 3;
    const float* src = x + (size_t)(mb * 16 + r) * Kc + kb * 32 + c * 8;
    float4 f0 = *(const float4*)src;
    float4 f1 = *(const float4*)(src + 4);
    unsigned short u[8];
    u[0] = f2bf(f0.x); u[1] = f2bf(f0.y); u[2] = f2bf(f0.z); u[3] = f2bf(f0.w);
    u[4] = f2bf(f1.x); u[5] = f2bf(f1.y); u[6] = f2bf(f1.z); u[7] = f2bf(f1.w);
    *(uint4*)(Ap + (size_t)t * 512 + (c * 16 + r) * 8) = *(uint4*)u;
}

// ---------------- W fp32 [K][N] -> packed bf16 fragments (transposed) ----------------
__global__ void transpose_convert_packed(const float* __restrict__ W,
                                         unsigned short* __restrict__ Bp,
                                         int K, int N) {
    __shared__ float tile[32][33];
    const int tx = threadIdx.x, ty = threadIdx.y;
    const int n0 = blockIdx.x * 32, k0 = blockIdx.y * 32;
    for (int i = ty; i < 32; i += 8)
        tile[i][tx] = W[(size_t)(k0 + i) * N + n0 + tx];
    __syncthreads();
    const int t = ty * 32 + tx;
    const int h = t >> 7, rr = t & 127, lane = rr >> 1, half = rr & 1;
    const int fq = lane >> 4, fn = lane & 15;
    unsigned short u[4];
    #pragma unroll
    for (int j = 0; j < 4; ++j)
        u[j] = f2bf(tile[fq * 8 + half * 4 + j][h * 16 + fn]);
    size_t tileIdx = (size_t)((n0 >> 4) + h) * (K >> 5) + (k0 >> 5);
    *(uint2*)(Bp + tileIdx * 512 + lane * 8 + half * 4) = *(uint2*)u;
}

// ---------------- LDS-staged bf16 MFMA GEMM, BK=64 (2 k-tiles / barrier-pair) ----
// Round-0 verified structure (128x128 block, 4 waves, 64x64/wave, 4 blocks/CU)
// with the K-loop unrolled x2: per iteration stage 32 tiles (8 gloads/wave),
// one __syncthreads pair, 32 MFMA/wave. Halves the 64 barrier-drain events
// that the m97 analysis identifies as the ~20% stall, while keeping the
// 4-block/CU TLP that made round-0 fastest (32 KB LDS; m132's regression was
// the 64 KB -> 2 blocks/CU cliff, avoided here). K accumulation order is
// unchanged (k-tiles 0,1,2,... sequential) -> numerics identical to round 0.
template <bool OUT_BF16>
__global__ __launch_bounds__(256, 4) void lds_gemm_kernel(
    const unsigned short* __restrict__ Ap,
    const unsigned short* __restrict__ Bp,
    const float* __restrict__ bias,
    void* __restrict__ Cout,
    int M, int N, int K, int NB) {
    __shared__ unsigned short sA[16 * 512];   // [mt*2+s][512]  (s = k-subtile)
    __shared__ unsigned short sB[16 * 512];   // [nt*2+s][512]
    const int KB = K >> 5;                    // 32-wide k-tiles
    const int MB = M >> 7;
    const int id   = blockIdx.x;
    const int xcd  = id & 7;
    const int per  = id >> 3;
    const int MSTR = MB >> 3;
    const int byl  = per & 7;
    const int bx   = (per >> 3) % NB;
    const int pass = per / (8 * NB);
    const int by   = xcd * MSTR + pass * 8 + byl;

    const int w    = threadIdx.x >> 6;
    const int lane = threadIdx.x & 63;
    const int m0 = by * 128;
    const int n0 = bx * 128;
    const int wm = (w >> 1) * 64;
    const int wn = (w & 1) * 64;

    // staging: wave w owns LDS tiles {4w..4w+3} of A and of B.
    // LDS tile t -> (mt = t>>1, s = t&1); global k-tile = 2j + s.
    const unsigned short* gA[4];
    const unsigned short* gB[4];
    unsigned short* lA[4];
    unsigned short* lB[4];
    #pragma unroll
    for (int i = 0; i < 4; ++i) {
        const int t  = w * 4 + i;
        const int mt = t >> 1, s = t & 1;
        gA[i] = Ap + ((size_t)(by * 8 + mt) * KB + s) * 512 + lane * 8;
        gB[i] = Bp + ((size_t)(bx * 8 + mt) * KB + s) * 512 + lane * 8;
        lA[i] = sA + t * 512;
        lB[i] = sB + t * 512;
    }

    // fragment read pointers (linear in lane -> conflict-free ds_read_b128)
    const unsigned short* aP = sA + (wm >> 4) * 2 * 512 + lane * 8;
    const unsigned short* bP = sB + (wn >> 4) * 2 * 512 + lane * 8;

    const f32x4 zero4 = {0.f, 0.f, 0.f, 0.f};
    f32x4 acc[4][4];
    #pragma unroll
    for (int i = 0; i < 4; ++i)
        #pragma unroll
        for (int j = 0; j < 4; ++j) acc[i][j] = zero4;

    const int NIT = K >> 6;   // BK=64 iterations
    #pragma unroll 1
    for (int jt = 0; jt < NIT; ++jt) {
        #pragma unroll
        for (int i = 0; i < 4; ++i) {
            load_lds16(gA[i], lA[i]);
            load_lds16(gB[i], lB[i]);
        }
        #pragma unroll
        for (int i = 0; i < 4; ++i) { gA[i] += 1024; gB[i] += 1024; }
        __syncthreads();   // drains DMA (vmcnt) + aligns waves

        #pragma unroll
        for (int kk = 0; kk < 2; ++kk) {
            bf16x8 af[4], bfr[4];
            #pragma unroll
            for (int mi = 0; mi < 4; ++mi)
                af[mi]  = *(const bf16x8*)(aP + (mi * 2 + kk) * 512);
            #pragma unroll
            for (int ni = 0; ni < 4; ++ni)
                bfr[ni] = *(const bf16x8*)(bP + (ni * 2 + kk) * 512);
            #pragma unroll
            for (int mi = 0; mi < 4; ++mi)
                #pragma unroll
                for (int ni = 0; ni < 4; ++ni)
                    acc[mi][ni] = __builtin_amdgcn_mfma_f32_16x16x32_bf16(
                        af[mi], bfr[ni], acc[mi][ni], 0, 0, 0);
        }
        __syncthreads();   // LDS consumed before next staging overwrites
    }

    // epilogue: D row = (lane>>4)*4 + reg, col = lane&15
    const int fr = lane & 15;
    const int fq = lane >> 4;
    #pragma unroll
    for (int mi = 0; mi < 4; ++mi) {
        #pragma unroll
        for (int ni = 0; ni < 4; ++ni) {
            int row = m0 + wm + mi * 16 + fq * 4;
            int col = n0 + wn + ni * 16 + fr;
            float bb = bias[col];
            #pragma unroll
            for (int r = 0; r < 4; ++r) {
                float v = acc[mi][ni][r] + bb;
                if (OUT_BF16)
                    ((unsigned short*)Cout)[(size_t)(row + r) * N + col] = f2bf(v);
                else
                    ((float*)Cout)[(size_t)(row + r) * N + col] = v;
            }
        }
    }
}

// ---------------- per-token head-axis attention, MFMA, packed-fragment out ----------------
// Exact round-0 verified version. One wave per token; output written directly
// in packed-fragment layout so it feeds lds_gemm as A (no repack pass).
__global__ __launch_bounds__(256) void attn_mfma_kernel(
    const unsigned short* __restrict__ qkv,
    unsigned short* __restrict__ attP) {
    __shared__ char smem[4 * 3584];
    const int w    = threadIdx.x >> 6;
    const int lane = threadIdx.x & 63;
    const int m    = lane & 15;
    const int q    = lane >> 4;
    const int row  = blockIdx.x * 4 + w;
    unsigned short* sV = (unsigned short*)(smem + w * 3584);        // [16][72] bf16
    float*          sP = (float*)(smem + w * 3584 + 2304);          // [16][20] fp32

    const unsigned short* src = qkv + (size_t)row * 3072;

    bf16x8 aq0 = *(const bf16x8*)(src + m * 64 + q * 8);
    bf16x8 aq1 = *(const bf16x8*)(src + m * 64 + 32 + q * 8);
    bf16x8 bk0 = *(const bf16x8*)(src + 1024 + m * 64 + q * 8);
    bf16x8 bk1 = *(const bf16x8*)(src + 1024 + m * 64 + 32 + q * 8);

    #pragma unroll
    for (int t = 0; t < 2; ++t) {
        int G = t * 64 + lane;
        int r = G >> 3, p = G & 7;
        *(uint4*)(sV + r * 72 + p * 8) = *(const uint4*)(src + 2048 + G * 8);
    }

    f32x4 s = {0.f, 0.f, 0.f, 0.f};
    s = __builtin_amdgcn_mfma_f32_16x16x32_bf16(aq0, bk0, s, 0, 0, 0);
    s = __builtin_amdgcn_mfma_f32_16x16x32_bf16(aq1, bk1, s, 0, 0, 0);

    #pragma unroll
    for (int r = 0; r < 4; ++r) {
        float t0 = s[r] * 0.125f;
        float mx = t0;
        mx = fmaxf(mx, __shfl_xor(mx, 1));
        mx = fmaxf(mx, __shfl_xor(mx, 2));
        mx = fmaxf(mx, __shfl_xor(mx, 4));
        mx = fmaxf(mx, __shfl_xor(mx, 8));
        float e = __expf(t0 - mx);
        float su = e;
        su += __shfl_xor(su, 1);
        su += __shfl_xor(su, 2);
        su += __shfl_xor(su, 4);
        su += __shfl_xor(su, 8);
        sP[(q * 4 + r) * 20 + m] = e / su;
    }
    __syncthreads();

    const float* pr = sP + m * 20 + (q & 1) * 8;
    float4 pf0 = *(const float4*)(pr);
    float4 pf1 = *(const float4*)(pr + 4);
    const bool act = (q < 2);
    union { unsigned short u[8]; bf16x8 b; } pa;
    pa.u[0] = act ? f2bf(pf0.x) : 0;
    pa.u[1] = act ? f2bf(pf0.y) : 0;
    pa.u[2] = act ? f2bf(pf0.z) : 0;
    pa.u[3] = act ? f2bf(pf0.w) : 0;
    pa.u[4] = act ? f2bf(pf1.x) : 0;
    pa.u[5] = act ? f2bf(pf1.y) : 0;
    pa.u[6] = act ? f2bf(pf1.z) : 0;
    pa.u[7] = act ? f2bf(pf1.w) : 0;

    const unsigned short* vb = sV + (q & 1) * 8 * 72;
    const size_t tileBase = (size_t)(row >> 4) * 32 * 512;   // token's m-block row (KB=32)
    const int fr_tok = row & 15;
    #pragma unroll
    for (int c4 = 0; c4 < 4; ++c4) {
        union { unsigned short u[8]; bf16x8 b; } vf;
        #pragma unroll
        for (int j = 0; j < 8; ++j) vf.u[j] = vb[j * 72 + c4 * 16 + m];
        f32x4 o = {0.f, 0.f, 0.f, 0.f};
        o = __builtin_amdgcn_mfma_f32_16x16x32_bf16(pa.b, vf.b, o, 0, 0, 0);
        #pragma unroll
        for (int r = 0; r < 4; ++r) {
            int col = (q * 4 + r) * 64 + c4 * 16 + m;        // k index in [0,1024)
            size_t off = tileBase + (size_t)(col >> 5) * 512
                       + (((col >> 3) & 3) * 16 + fr_tok) * 8 + (col & 7);
            attP[off] = f2bf(o[r]);
        }
    }
}

extern "C" void kernel_launch(void* const* d_in, const int* in_sizes, int n_in,
                              void* d_out, int out_size, void* d_ws, size_t ws_size,
                              hipStream_t stream) {
    const float* x    = (const float*)d_in[0];
    const float* Wqkv = (const float*)d_in[1];
    const float* bqkv = (const float*)d_in[2];
    const float* Wout = (const float*)d_in[3];
    const float* bout = (const float*)d_in[4];
    float* out = (float*)d_out;

    // workspace: xp 32M | Wqkv_p 6M | Wout_p 2M | qkv 96M = ~136 MB
    char* ws = (char*)d_ws;
    unsigned short* xp   = (unsigned short*)ws;                 ws += (size_t)Mc * Kc * 2;
    unsigned short* Wqkp = (unsigned short*)ws;                 ws += (size_t)N1c * Kc * 2;
    unsigned short* Wop  = (unsigned short*)ws;                 ws += (size_t)Cc * Kc * 2;
    unsigned short* qkv  = (unsigned short*)ws;
    unsigned short* attP = xp;   // alias: xp dead after GEMM1

    // 1) x -> packed bf16 fragments
    convert_x_packed<<<(Mc / 16) * KBc / 4, 256, 0, stream>>>(x, xp);
    // 2) weights -> packed bf16 fragments (transposed)
    transpose_convert_packed<<<dim3(N1c / 32, Kc / 32), dim3(32, 8), 0, stream>>>(Wqkv, Wqkp, Kc, N1c);
    transpose_convert_packed<<<dim3(Cc / 32, Kc / 32), dim3(32, 8), 0, stream>>>(Wout, Wop, Kc, Cc);
    // 3) qkv = x @ W_qkv + b_qkv   (bf16 row-major out)
    lds_gemm_kernel<true><<<(N1c / 128) * (Mc / 128), 256, 0, stream>>>(
        xp, Wqkp, bqkv, qkv, Mc, N1c, Kc, N1c / 128);
    // 4) head-axis attention per token (MFMA), writes packed-fragment A
    attn_mfma_kernel<<<Mc / 4, 256, 0, stream>>>(qkv, attP);
    // 5) out = att @ W_out + b_out (fp32 row-major out)
    lds_gemm_kernel<false><<<(Cc / 128) * (Mc / 128), 256, 0, stream>>>(
        attP, Wop, bout, out, Mc, Cc, Kc, Cc / 128);
}